// Round 2
// baseline (733.057 us; speedup 1.0000x reference)
//
#include <hip/hip_runtime.h>
#include <math.h>

#define NPED 512
#define OBS 8
#define PRED 12
#define HE 8
#define HD 16
#define EMB 16
#define NZ 8
#define NSEQ 8

typedef const float* fp;

__device__ __forceinline__ float sigm(float x){ return 1.0f/(1.0f+expf(-x)); }

// workspace layout (floats)
#define WS_H    0                    // 512*16 decoder h (starts as dec_h)
#define WS_C    (WS_H + NPED*HD)     // 512*16
#define WS_CTX  (WS_C + NPED*HD)     // 512*16
#define WS_POS  (WS_CTX + NPED*HD)   // 512*2
#define WS_HB   (WS_POS + NPED*2)    // 512*64 : HB[j][u] = h[j] . Wm1[u,16:32]
// total 58368 floats = 228 KiB

// ---------------- encoder: 8 LSTM steps, one thread per pedestrian ----------
__global__ void enc_kernel(fp traj, fp obs_pos, fp h0, fp c0, fp noise,
                           fp Wenc, fp benc, fp Wih, fp Whh, fp bih, fp bhh,
                           const int* sse, float* ws)
{
    __shared__ float s_wenc[32], s_benc[16], s_wih[512], s_whh[256];
    __shared__ float s_bih[32], s_bhh[32], s_noise[64];
    __shared__ int   s_starts[NSEQ];
    int tid = threadIdx.x;
    for (int i = tid; i < 32;  i += blockDim.x) s_wenc[i] = Wenc[i];
    for (int i = tid; i < 16;  i += blockDim.x) s_benc[i] = benc[i];
    for (int i = tid; i < 512; i += blockDim.x) s_wih[i]  = Wih[i];
    for (int i = tid; i < 256; i += blockDim.x) s_whh[i]  = Whh[i];
    for (int i = tid; i < 32;  i += blockDim.x) { s_bih[i] = bih[i]; s_bhh[i] = bhh[i]; }
    for (int i = tid; i < 64;  i += blockDim.x) s_noise[i] = noise[i];
    for (int i = tid; i < NSEQ; i += blockDim.x) s_starts[i] = sse[i*2];
    __syncthreads();

    int n = blockIdx.x * blockDim.x + tid;
    if (n >= NPED) return;

    float h[HE], c[HE];
    for (int k = 0; k < HE; k++) { h[k] = h0[n*HE+k]; c[k] = c0[n*HE+k]; }

    for (int t = 0; t < OBS; t++) {
        float x0 = traj[(t*NPED+n)*2+0];
        float x1 = traj[(t*NPED+n)*2+1];
        float e[EMB];
        for (int k = 0; k < EMB; k++) {
            float v = s_wenc[k*2]*x0 + s_wenc[k*2+1]*x1 + s_benc[k];
            e[k] = v > 0.f ? v : 0.f;
        }
        float g[4*HE];
        for (int r = 0; r < 4*HE; r++) {
            float a = s_bih[r] + s_bhh[r];
            for (int k = 0; k < EMB; k++) a += s_wih[r*EMB+k]*e[k];
            for (int k = 0; k < HE;  k++) a += s_whh[r*HE+k]*h[k];
            g[r] = a;
        }
        for (int k = 0; k < HE; k++) {
            float ig = sigm(g[k]), fg = sigm(g[HE+k]);
            float gg = tanhf(g[2*HE+k]), og = sigm(g[3*HE+k]);
            c[k] = fg*c[k] + ig*gg;
            h[k] = og*tanhf(c[k]);
        }
    }
    // seq id = searchsorted(starts, n, 'right') - 1
    int cnt = 0;
    for (int s2 = 0; s2 < NSEQ; s2++) cnt += (s_starts[s2] <= n) ? 1 : 0;
    int sid = cnt - 1;

    for (int k = 0; k < HE; k++) ws[WS_H + n*HD + k] = h[k];
    for (int k = 0; k < NZ; k++) ws[WS_H + n*HD + HE + k] = s_noise[sid*NZ+k];
    for (int k = 0; k < HD; k++) { ws[WS_C + n*HD + k] = 0.f; ws[WS_CTX + n*HD + k] = 0.f; }
    ws[WS_POS + n*2 + 0] = obs_pos[((OBS-1)*NPED+n)*2 + 0];
    ws[WS_POS + n*2 + 1] = obs_pos[((OBS-1)*NPED+n)*2 + 1];
}

// ---- decoder step: emit out[t-1], update pos, LSTM, precompute HB ----------
__global__ void step_kernel(int t, int do_lstm,
                            fp Wdec, fp bdec, fp Wihp, fp Whhp, fp bihp, fp bhhp,
                            fp Wout, fp bout, fp Wm1,
                            float* ws, float* dout)
{
    __shared__ float s_wdec[288], s_bdec[16], s_wih[1024], s_whh[1024];
    __shared__ float s_bih[64], s_bhh[64], s_wout[32], s_bout[2], s_wm1h[1024];
    int tid = threadIdx.x;
    for (int i = tid; i < 288;  i += blockDim.x) s_wdec[i] = Wdec[i];
    for (int i = tid; i < 16;   i += blockDim.x) s_bdec[i] = bdec[i];
    for (int i = tid; i < 1024; i += blockDim.x) { s_wih[i] = Wihp[i]; s_whh[i] = Whhp[i]; }
    for (int i = tid; i < 64;   i += blockDim.x) { s_bih[i] = bihp[i]; s_bhh[i] = bhhp[i]; }
    for (int i = tid; i < 32;   i += blockDim.x) s_wout[i] = Wout[i];
    for (int i = tid; i < 2;    i += blockDim.x) s_bout[i] = bout[i];
    for (int i = tid; i < 1024; i += blockDim.x) { int u = i >> 4, k = i & 15; s_wm1h[i] = Wm1[u*32 + 16 + k]; }
    __syncthreads();

    int n = blockIdx.x * blockDim.x + tid;
    if (n >= NPED) return;

    float ctxv[HD], hv[HD];
    for (int k = 0; k < HD; k++) { ctxv[k] = ws[WS_CTX + n*HD + k]; hv[k] = ws[WS_H + n*HD + k]; }

    float o0 = 0.f, o1 = 0.f;
    if (t > 0) {
        float o[2];
        for (int d = 0; d < 2; d++) {
            float a = s_bout[d];
            for (int k = 0; k < HD; k++) a += s_wout[d*HD+k]*(ctxv[k]+hv[k]);
            o[d] = tanhf(a)*4.4f;
        }
        o0 = o[0]; o1 = o[1];
        dout[((t-1)*NPED + n)*2 + 0] = o0;
        dout[((t-1)*NPED + n)*2 + 1] = o1;
        if (do_lstm) {
            ws[WS_POS + n*2 + 0] += o0;
            ws[WS_POS + n*2 + 1] += o1;
        }
    }
    if (!do_lstm) return;

    // e = relu(W_dec @ [ctx, out] + b_dec)
    float e[EMB];
    for (int k = 0; k < EMB; k++) {
        float a = s_bdec[k];
        for (int d = 0; d < HD; d++) a += s_wdec[k*18+d]*ctxv[d];
        a += s_wdec[k*18+16]*o0 + s_wdec[k*18+17]*o1;
        e[k] = a > 0.f ? a : 0.f;
    }
    float cv[HD];
    for (int k = 0; k < HD; k++) cv[k] = ws[WS_C + n*HD + k];
    float g[4*HD];
    for (int r = 0; r < 4*HD; r++) {
        float a = s_bih[r] + s_bhh[r];
        for (int k = 0; k < EMB; k++) a += s_wih[r*EMB+k]*e[k];
        for (int k = 0; k < HD;  k++) a += s_whh[r*HD+k]*hv[k];
        g[r] = a;
    }
    for (int k = 0; k < HD; k++) {
        float ig = sigm(g[k]), fg = sigm(g[HD+k]);
        float gg = tanhf(g[2*HD+k]), og = sigm(g[3*HD+k]);
        cv[k] = fg*cv[k] + ig*gg;
        hv[k] = og*tanhf(cv[k]);
    }
    for (int k = 0; k < HD; k++) { ws[WS_H + n*HD + k] = hv[k]; ws[WS_C + n*HD + k] = cv[k]; }

    // HB[n][u] = h[n] . Wm1[u, 16:32]   (i-independent part of pool's m1)
    for (int u = 0; u < 64; u++) {
        float a = 0.f;
        for (int k = 0; k < HD; k++) a += s_wm1h[u*HD+k]*hv[k];
        ws[WS_HB + n*64 + u] = a;
    }
}

// ---------------- social pool: one block per row i, online softmax ----------
__global__ void pool_kernel(int t, const int* nei,
                            fp Wse, fp bse, fp Wm1, fp bm1, fp Wm2, fp bm2,
                            fp Watt, fp batt, float* ws)
{
    __shared__ float s_A0[64], s_A1[64], s_bb[64];
    __shared__ float s_wm2[1024], s_bm2[16], s_watt[16], s_batt;
    __shared__ float s_posx[NPED], s_posy[NPED];
    __shared__ float s_red[4*18];
    int tid = threadIdx.x;

    if (tid < 64) {   // fold W_se into W_m1:  A = Wm1[:, :16] @ W_se, bb = b_m1 + Wm1[:, :16] @ b_se
        float a0 = 0.f, a1 = 0.f, bb = bm1[tid];
        for (int k = 0; k < 16; k++) {
            float w = Wm1[tid*32 + k];
            a0 += w * Wse[k*2 + 0];
            a1 += w * Wse[k*2 + 1];
            bb += w * bse[k];
        }
        s_A0[tid] = a0; s_A1[tid] = a1; s_bb[tid] = bb;
    }
    for (int i = tid; i < 1024; i += blockDim.x) s_wm2[i] = Wm2[i];
    if (tid < 16) { s_bm2[tid] = bm2[tid]; s_watt[tid] = Watt[tid]; }
    if (tid == 0) s_batt = batt[0];
    for (int j = tid; j < NPED; j += blockDim.x) {
        s_posx[j] = ws[WS_POS + j*2 + 0];
        s_posy[j] = ws[WS_POS + j*2 + 1];
    }
    __syncthreads();

    int i = blockIdx.x;
    float pix = s_posx[i], piy = s_posy[i];
    float m = -INFINITY, l = 0.f, acc[16];
    #pragma unroll
    for (int v = 0; v < 16; v++) acc[v] = 0.f;

    const int* neirow = nei + ((size_t)t*NPED + i)*NPED;
    for (int j = tid; j < NPED; j += blockDim.x) {
        if (neirow[j] <= 0) continue;
        float cx = pix - s_posx[j], cy = piy - s_posy[j];
        float pre[16];
        #pragma unroll
        for (int v = 0; v < 16; v++) pre[v] = 0.f;
        const float4* HB4 = reinterpret_cast<const float4*>(ws + WS_HB + j*64);
        #pragma unroll 4
        for (int uq = 0; uq < 16; uq++) {
            float4 hb = HB4[uq];
            const float* hbp = (const float*)&hb;
            #pragma unroll
            for (int uu = 0; uu < 4; uu++) {
                int u = uq*4 + uu;
                float h1 = s_bb[u] + s_A0[u]*cx + s_A1[u]*cy + hbp[uu];
                h1 = fmaxf(h1, 0.f);
                #pragma unroll
                for (int v = 0; v < 16; v++) pre[v] += s_wm2[v*64 + u]*h1;
            }
        }
        float s = s_batt;
        #pragma unroll
        for (int v = 0; v < 16; v++) {
            float p = pre[v] + s_bm2[v];
            p = fmaxf(p, 0.f);
            pre[v] = p;
            s += s_watt[v]*p;
        }
        // online softmax accumulate
        if (s <= m) {
            float w = expf(s - m);
            l += w;
            #pragma unroll
            for (int v = 0; v < 16; v++) acc[v] += w*pre[v];
        } else {
            float sc = (l > 0.f) ? expf(m - s) : 0.f;
            l = l*sc + 1.f;
            #pragma unroll
            for (int v = 0; v < 16; v++) acc[v] = acc[v]*sc + pre[v];
            m = s;
        }
    }

    // wave-level combine (64 lanes)
    for (int off = 32; off >= 1; off >>= 1) {
        float om = __shfl_down(m, off);
        float ol = __shfl_down(l, off);
        float oa[16];
        #pragma unroll
        for (int v = 0; v < 16; v++) oa[v] = __shfl_down(acc[v], off);
        float nm = fmaxf(m, om);
        float e1 = (l  > 0.f) ? expf(m  - nm) : 0.f;
        float e2 = (ol > 0.f) ? expf(om - nm) : 0.f;
        l = l*e1 + ol*e2;
        #pragma unroll
        for (int v = 0; v < 16; v++) acc[v] = acc[v]*e1 + oa[v]*e2;
        m = nm;
    }
    int wid = tid >> 6, lane = tid & 63;
    if (lane == 0) {
        s_red[wid*18 + 0] = m; s_red[wid*18 + 1] = l;
        #pragma unroll
        for (int v = 0; v < 16; v++) s_red[wid*18 + 2 + v] = acc[v];
    }
    __syncthreads();
    if (tid == 0) {
        float M = s_red[0], L = s_red[1], A[16];
        #pragma unroll
        for (int v = 0; v < 16; v++) A[v] = s_red[2+v];
        for (int w2 = 1; w2 < 4; w2++) {
            float om = s_red[w2*18], ol = s_red[w2*18+1];
            float nm = fmaxf(M, om);
            float e1 = (L  > 0.f) ? expf(M  - nm) : 0.f;
            float e2 = (ol > 0.f) ? expf(om - nm) : 0.f;
            L = L*e1 + ol*e2;
            #pragma unroll
            for (int v = 0; v < 16; v++) A[v] = A[v]*e1 + s_red[w2*18+2+v]*e2;
            M = nm;
        }
        for (int v = 0; v < 16; v++) ws[WS_CTX + i*HD + v] = (L > 0.f) ? A[v]/L : 0.f;
    }
}

extern "C" void kernel_launch(void* const* d_in, const int* in_sizes, int n_in,
                              void* d_out, int out_size, void* d_ws, size_t ws_size,
                              hipStream_t stream)
{
    fp traj = (fp)d_in[0];
    fp obs  = (fp)d_in[1];
    fp h0   = (fp)d_in[3];
    fp c0   = (fp)d_in[4];
    fp noise= (fp)d_in[5];
    fp Wenc = (fp)d_in[6];  fp benc = (fp)d_in[7];
    fp Wdec = (fp)d_in[8];  fp bdec = (fp)d_in[9];
    fp Wiht = (fp)d_in[10]; fp Whht = (fp)d_in[11];
    fp biht = (fp)d_in[12]; fp bhht = (fp)d_in[13];
    fp Wihp = (fp)d_in[14]; fp Whhp = (fp)d_in[15];
    fp bihp = (fp)d_in[16]; fp bhhp = (fp)d_in[17];
    fp Wout = (fp)d_in[18]; fp bout = (fp)d_in[19];
    fp Wse  = (fp)d_in[20]; fp bse  = (fp)d_in[21];
    fp Wm1  = (fp)d_in[22]; fp bm1  = (fp)d_in[23];
    fp Wm2  = (fp)d_in[24]; fp bm2  = (fp)d_in[25];
    fp Watt = (fp)d_in[26]; fp batt = (fp)d_in[27];
    const int* sse = (const int*)d_in[28];
    const int* nei = (const int*)d_in[29];
    float* ws = (float*)d_ws;
    float* out = (float*)d_out;

    hipLaunchKernelGGL(enc_kernel, dim3(8), dim3(64), 0, stream,
                       traj, obs, h0, c0, noise, Wenc, benc, Wiht, Whht, biht, bhht, sse, ws);
    for (int t = 0; t < PRED; t++) {
        hipLaunchKernelGGL(step_kernel, dim3(4), dim3(128), 0, stream,
                           t, 1, Wdec, bdec, Wihp, Whhp, bihp, bhhp, Wout, bout, Wm1, ws, out);
        hipLaunchKernelGGL(pool_kernel, dim3(NPED), dim3(256), 0, stream,
                           t, nei, Wse, bse, Wm1, bm1, Wm2, bm2, Watt, batt, ws);
    }
    hipLaunchKernelGGL(step_kernel, dim3(4), dim3(128), 0, stream,
                       12, 0, Wdec, bdec, Wihp, Whhp, bihp, bhhp, Wout, bout, Wm1, ws, out);
}

// Round 3
// 359.426 us; speedup vs baseline: 2.0395x; 2.0395x over previous
//
#include <hip/hip_runtime.h>
#include <math.h>

#define NPED 512
#define OBS 8
#define PRED 12
#define HE 8
#define HD 16
#define EMB 16
#define NZ 8
#define NSEQ 8

typedef const float* fp;

__device__ __forceinline__ float frcp(float x){ return __builtin_amdgcn_rcpf(x); }
__device__ __forceinline__ float sigm(float x){ return frcp(1.0f + __expf(-x)); }
__device__ __forceinline__ float tanh_f(float x){ return 1.0f - 2.0f*frcp(__expf(2.0f*x) + 1.0f); }

// workspace layout (floats)
#define WS_H    0                    // 512*16 decoder h (starts as dec_h)
#define WS_C    (WS_H + NPED*HD)     // 512*16
#define WS_CTX  (WS_C + NPED*HD)     // 512*16
#define WS_POS  (WS_CTX + NPED*HD)   // 512*2
#define WS_HB   (WS_POS + NPED*2)    // 512*64 : HB[j][u] = h[j] . Wm1[u,16:32]

__device__ __forceinline__ void fma4(float4& a, const float4 w, float s){
    a.x += w.x*s; a.y += w.y*s; a.z += w.z*s; a.w += w.w*s;
}

// ---------------- encoder: 8 lanes per pedestrian (lane = hidden unit) -----
__global__ __launch_bounds__(256) void enc_kernel(
        fp traj, fp obs_pos, fp h0, fp c0, fp noise,
        fp Wenc, fp benc, fp Wih, fp Whh, fp bih, fp bhh,
        const int* sse, float* ws)
{
    __shared__ float s_wenc[32], s_benc[16], s_wih[32*17], s_whh[32*9];
    __shared__ float s_bih[32], s_bhh[32];
    int tid = threadIdx.x;
    if (tid < 32) { s_wenc[tid] = Wenc[tid]; s_bih[tid] = bih[tid]; s_bhh[tid] = bhh[tid]; }
    if (tid < 16) s_benc[tid] = benc[tid];
    for (int i = tid; i < 512; i += 256) s_wih[(i>>4)*17 + (i&15)] = Wih[i];
    if (tid < 256) { int i = tid; if (i < 256) s_whh[(i>>3)*9 + (i&7)] = Whh[i]; }
    __syncthreads();

    int n = blockIdx.x*32 + (tid>>3);
    int k = tid & 7;

    float h = h0[n*HE+k], c = c0[n*HE+k];

    for (int t = 0; t < OBS; t++) {
        float x0 = traj[(t*NPED+n)*2+0];
        float x1 = traj[(t*NPED+n)*2+1];
        float g0 = s_bih[k]    + s_bhh[k];
        float g1 = s_bih[8+k]  + s_bhh[8+k];
        float g2 = s_bih[16+k] + s_bhh[16+k];
        float g3 = s_bih[24+k] + s_bhh[24+k];
        #pragma unroll
        for (int d = 0; d < EMB; d++) {
            float e = s_wenc[d*2]*x0 + s_wenc[d*2+1]*x1 + s_benc[d];
            e = fmaxf(e, 0.f);
            g0 += s_wih[(k)*17+d]*e;
            g1 += s_wih[(8+k)*17+d]*e;
            g2 += s_wih[(16+k)*17+d]*e;
            g3 += s_wih[(24+k)*17+d]*e;
        }
        #pragma unroll
        for (int d = 0; d < HE; d++) {
            float hv = __shfl(h, d, 8);
            g0 += s_whh[(k)*9+d]*hv;
            g1 += s_whh[(8+k)*9+d]*hv;
            g2 += s_whh[(16+k)*9+d]*hv;
            g3 += s_whh[(24+k)*9+d]*hv;
        }
        c = sigm(g1)*c + sigm(g0)*tanh_f(g2);
        h = sigm(g3)*tanh_f(c);
    }

    int cnt = 0;
    #pragma unroll
    for (int s2 = 0; s2 < NSEQ; s2++) cnt += (sse[s2*2] <= n) ? 1 : 0;
    int sid = cnt - 1;

    ws[WS_H + n*HD + k]     = h;
    ws[WS_H + n*HD + 8 + k] = noise[sid*NZ + k];
    ws[WS_C + n*HD + k] = 0.f;   ws[WS_C + n*HD + 8 + k] = 0.f;
    ws[WS_CTX + n*HD + k] = 0.f; ws[WS_CTX + n*HD + 8 + k] = 0.f;
    if (k < 2) ws[WS_POS + n*2 + k] = obs_pos[((OBS-1)*NPED+n)*2 + k];
}

// ---- decoder step: 16 lanes per pedestrian -------------------------------
__global__ __launch_bounds__(256) void step_kernel(
        int t, int do_lstm,
        fp Wdec, fp bdec, fp Wihp, fp Whhp, fp bihp, fp bhhp,
        fp Wout, fp bout, fp Wm1,
        float* ws, float* dout)
{
    __shared__ float s_wdec[16*19], s_wih[64*17], s_whh[64*17], s_wm1h[64*17];
    __shared__ float s_bih[64], s_bhh[64], s_bdec[16], s_wout[32], s_bout[2];
    int tid = threadIdx.x;
    for (int i = tid; i < 288; i += 256) s_wdec[(i/18)*19 + (i%18)] = Wdec[i];
    for (int i = tid; i < 1024; i += 256) {
        int r = i>>4, d = i&15;
        s_wih[r*17+d]  = Wihp[i];
        s_whh[r*17+d]  = Whhp[i];
        s_wm1h[r*17+d] = Wm1[r*32 + 16 + d];
    }
    if (tid < 64) { s_bih[tid] = bihp[tid]; s_bhh[tid] = bhhp[tid]; }
    if (tid < 16) s_bdec[tid] = bdec[tid];
    if (tid < 32) s_wout[tid] = Wout[tid];
    if (tid < 2)  s_bout[tid] = bout[tid];
    __syncthreads();

    int n = blockIdx.x*16 + (tid>>4);
    int k = tid & 15;

    float ctx = ws[WS_CTX + n*HD + k];
    float h   = ws[WS_H + n*HD + k];

    float o0 = 0.f, o1 = 0.f;
    if (t > 0) {
        float ch = ctx + h;
        float r0 = s_wout[k]*ch, r1 = s_wout[16+k]*ch;
        #pragma unroll
        for (int off = 8; off >= 1; off >>= 1) {
            r0 += __shfl_xor(r0, off, 16);
            r1 += __shfl_xor(r1, off, 16);
        }
        o0 = tanh_f(s_bout[0] + r0)*4.4f;
        o1 = tanh_f(s_bout[1] + r1)*4.4f;
        if (k == 0) dout[((t-1)*NPED + n)*2 + 0] = o0;
        if (k == 1) dout[((t-1)*NPED + n)*2 + 1] = o1;
        if (do_lstm) {
            if (k == 0) ws[WS_POS + n*2 + 0] += o0;
            if (k == 1) ws[WS_POS + n*2 + 1] += o1;
        }
    }
    if (!do_lstm) return;

    // e_k = relu(Wdec[k,:] . [ctx, o0, o1])
    float e = s_bdec[k];
    #pragma unroll
    for (int d = 0; d < HD; d++) {
        float cv = __shfl(ctx, d, 16);
        e += s_wdec[k*19 + d]*cv;
    }
    e += s_wdec[k*19+16]*o0 + s_wdec[k*19+17]*o1;
    e = fmaxf(e, 0.f);

    float c = ws[WS_C + n*HD + k];
    float g0 = s_bih[k]    + s_bhh[k];
    float g1 = s_bih[16+k] + s_bhh[16+k];
    float g2 = s_bih[32+k] + s_bhh[32+k];
    float g3 = s_bih[48+k] + s_bhh[48+k];
    #pragma unroll
    for (int d = 0; d < HD; d++) {
        float ev = __shfl(e, d, 16);
        float hv = __shfl(h, d, 16);
        g0 += s_wih[(k)*17+d]*ev    + s_whh[(k)*17+d]*hv;
        g1 += s_wih[(16+k)*17+d]*ev + s_whh[(16+k)*17+d]*hv;
        g2 += s_wih[(32+k)*17+d]*ev + s_whh[(32+k)*17+d]*hv;
        g3 += s_wih[(48+k)*17+d]*ev + s_whh[(48+k)*17+d]*hv;
    }
    c = sigm(g1)*c + sigm(g0)*tanh_f(g2);
    float hn = sigm(g3)*tanh_f(c);
    ws[WS_H + n*HD + k] = hn;
    ws[WS_C + n*HD + k] = c;

    // HB[n][u] = h_new . Wm1[u, 16:32], u = {k, 16+k, 32+k, 48+k}
    float hb0=0.f, hb1=0.f, hb2=0.f, hb3=0.f;
    #pragma unroll
    for (int d = 0; d < HD; d++) {
        float hv = __shfl(hn, d, 16);
        hb0 += s_wm1h[(k)*17+d]*hv;
        hb1 += s_wm1h[(16+k)*17+d]*hv;
        hb2 += s_wm1h[(32+k)*17+d]*hv;
        hb3 += s_wm1h[(48+k)*17+d]*hv;
    }
    ws[WS_HB + n*64 + k]      = hb0;
    ws[WS_HB + n*64 + 16 + k] = hb1;
    ws[WS_HB + n*64 + 32 + k] = hb2;
    ws[WS_HB + n*64 + 48 + k] = hb3;
}

// ---------------- social pool: one block per row i, online softmax ----------
__global__ __launch_bounds__(256) void pool_kernel(
        int t, const int* nei,
        fp Wse, fp bse, fp Wm1, fp bm1, fp Wm2, fp bm2,
        fp Watt, fp batt, float* ws)
{
    __shared__ float4 s_abb[64];      // {A0, A1, bb, 0}
    __shared__ float4 s_wm2t[64*4];   // [u][v] transposed, v contiguous
    __shared__ float4 s_bm24[4], s_watt4[4];
    __shared__ float s_batt;
    __shared__ float s_posx[NPED], s_posy[NPED];
    __shared__ float s_red[4*18];
    int tid = threadIdx.x;

    if (tid < 64) {   // fold W_se into W_m1
        float a0=0.f, a1=0.f, bb = bm1[tid];
        for (int kk = 0; kk < 16; kk++) {
            float w = Wm1[tid*32 + kk];
            a0 += w*Wse[kk*2+0]; a1 += w*Wse[kk*2+1]; bb += w*bse[kk];
        }
        s_abb[tid] = make_float4(a0, a1, bb, 0.f);
    }
    for (int i = tid; i < 1024; i += 256) {
        int u = i >> 4, v = i & 15;
        ((float*)s_wm2t)[u*16 + v] = Wm2[v*64 + u];
    }
    if (tid < 16) { ((float*)s_bm24)[tid] = bm2[tid]; ((float*)s_watt4)[tid] = Watt[tid]; }
    if (tid == 0) s_batt = batt[0];
    {
        const float2* p2 = (const float2*)(ws + WS_POS);
        for (int j = tid; j < NPED; j += 256) { float2 p = p2[j]; s_posx[j] = p.x; s_posy[j] = p.y; }
    }
    __syncthreads();

    int i = blockIdx.x;
    float pix = s_posx[i], piy = s_posy[i];
    float m = -INFINITY, l = 0.f;
    float4 acc[4];
    #pragma unroll
    for (int q = 0; q < 4; q++) acc[q] = make_float4(0.f,0.f,0.f,0.f);

    const int2* nei2 = (const int2*)(nei + ((size_t)t*NPED + i)*NPED);
    int2 nv = nei2[tid];
    #pragma unroll
    for (int jj = 0; jj < 2; jj++) {
        int act = (jj == 0) ? nv.x : nv.y;
        if (act <= 0) continue;
        int j = tid*2 + jj;
        float cx = pix - s_posx[j], cy = piy - s_posy[j];
        float4 pre[4] = { s_bm24[0], s_bm24[1], s_bm24[2], s_bm24[3] };
        const float4* HB4 = (const float4*)(ws + WS_HB + j*64);
        #pragma unroll
        for (int uq = 0; uq < 16; uq++) {
            float4 hb = HB4[uq];
            #define DO_U(q_, comp_) { \
                float4 ab = s_abb[uq*4+q_]; \
                float h1 = fmaxf(ab.z + ab.x*cx + ab.y*cy + (comp_), 0.f); \
                const float4* wrow = s_wm2t + (uq*4+q_)*4; \
                fma4(pre[0], wrow[0], h1); fma4(pre[1], wrow[1], h1); \
                fma4(pre[2], wrow[2], h1); fma4(pre[3], wrow[3], h1); }
            DO_U(0, hb.x) DO_U(1, hb.y) DO_U(2, hb.z) DO_U(3, hb.w)
            #undef DO_U
        }
        float s = s_batt;
        #pragma unroll
        for (int q = 0; q < 4; q++) {
            float4 p = pre[q];
            p.x = fmaxf(p.x,0.f); p.y = fmaxf(p.y,0.f); p.z = fmaxf(p.z,0.f); p.w = fmaxf(p.w,0.f);
            float4 wa = s_watt4[q];
            s += wa.x*p.x + wa.y*p.y + wa.z*p.z + wa.w*p.w;
            pre[q] = p;
        }
        float nm = fmaxf(m, s);
        float e1 = __expf(m - nm);   // m = -inf -> 0
        float e2 = __expf(s - nm);
        l = l*e1 + e2;
        #pragma unroll
        for (int q = 0; q < 4; q++) {
            acc[q].x = acc[q].x*e1 + pre[q].x*e2;
            acc[q].y = acc[q].y*e1 + pre[q].y*e2;
            acc[q].z = acc[q].z*e1 + pre[q].z*e2;
            acc[q].w = acc[q].w*e1 + pre[q].w*e2;
        }
        m = nm;
    }

    // wave-level combine (64 lanes)
    float* accp = (float*)acc;
    for (int off = 32; off >= 1; off >>= 1) {
        float om = __shfl_down(m, off);
        float ol = __shfl_down(l, off);
        float oa[16];
        #pragma unroll
        for (int v = 0; v < 16; v++) oa[v] = __shfl_down(accp[v], off);
        float nm = fmaxf(m, om);
        float e1 = (l  > 0.f) ? __expf(m  - nm) : 0.f;
        float e2 = (ol > 0.f) ? __expf(om - nm) : 0.f;
        l = l*e1 + ol*e2;
        #pragma unroll
        for (int v = 0; v < 16; v++) accp[v] = accp[v]*e1 + oa[v]*e2;
        m = nm;
    }
    int wid = tid >> 6, lane = tid & 63;
    if (lane == 0) {
        s_red[wid*18 + 0] = m; s_red[wid*18 + 1] = l;
        #pragma unroll
        for (int v = 0; v < 16; v++) s_red[wid*18 + 2 + v] = accp[v];
    }
    __syncthreads();
    if (tid == 0) {
        float M = s_red[0], L = s_red[1], A[16];
        #pragma unroll
        for (int v = 0; v < 16; v++) A[v] = s_red[2+v];
        for (int w2 = 1; w2 < 4; w2++) {
            float om = s_red[w2*18], ol = s_red[w2*18+1];
            float nm = fmaxf(M, om);
            float e1 = (L  > 0.f) ? __expf(M  - nm) : 0.f;
            float e2 = (ol > 0.f) ? __expf(om - nm) : 0.f;
            L = L*e1 + ol*e2;
            #pragma unroll
            for (int v = 0; v < 16; v++) A[v] = A[v]*e1 + s_red[w2*18+2+v]*e2;
            M = nm;
        }
        for (int v = 0; v < 16; v++) ws[WS_CTX + i*HD + v] = (L > 0.f) ? A[v]/L : 0.f;
    }
}

extern "C" void kernel_launch(void* const* d_in, const int* in_sizes, int n_in,
                              void* d_out, int out_size, void* d_ws, size_t ws_size,
                              hipStream_t stream)
{
    fp traj = (fp)d_in[0];
    fp obs  = (fp)d_in[1];
    fp h0   = (fp)d_in[3];
    fp c0   = (fp)d_in[4];
    fp noise= (fp)d_in[5];
    fp Wenc = (fp)d_in[6];  fp benc = (fp)d_in[7];
    fp Wdec = (fp)d_in[8];  fp bdec = (fp)d_in[9];
    fp Wiht = (fp)d_in[10]; fp Whht = (fp)d_in[11];
    fp biht = (fp)d_in[12]; fp bhht = (fp)d_in[13];
    fp Wihp = (fp)d_in[14]; fp Whhp = (fp)d_in[15];
    fp bihp = (fp)d_in[16]; fp bhhp = (fp)d_in[17];
    fp Wout = (fp)d_in[18]; fp bout = (fp)d_in[19];
    fp Wse  = (fp)d_in[20]; fp bse  = (fp)d_in[21];
    fp Wm1  = (fp)d_in[22]; fp bm1  = (fp)d_in[23];
    fp Wm2  = (fp)d_in[24]; fp bm2  = (fp)d_in[25];
    fp Watt = (fp)d_in[26]; fp batt = (fp)d_in[27];
    const int* sse = (const int*)d_in[28];
    const int* nei = (const int*)d_in[29];
    float* ws = (float*)d_ws;
    float* out = (float*)d_out;

    hipLaunchKernelGGL(enc_kernel, dim3(16), dim3(256), 0, stream,
                       traj, obs, h0, c0, noise, Wenc, benc, Wiht, Whht, biht, bhht, sse, ws);
    for (int t = 0; t < PRED; t++) {
        hipLaunchKernelGGL(step_kernel, dim3(32), dim3(256), 0, stream,
                           t, 1, Wdec, bdec, Wihp, Whhp, bihp, bhhp, Wout, bout, Wm1, ws, out);
        hipLaunchKernelGGL(pool_kernel, dim3(NPED), dim3(256), 0, stream,
                           t, nei, Wse, bse, Wm1, bm1, Wm2, bm2, Watt, batt, ws);
    }
    hipLaunchKernelGGL(step_kernel, dim3(32), dim3(256), 0, stream,
                       12, 0, Wdec, bdec, Wihp, Whhp, bihp, bhhp, Wout, bout, Wm1, ws, out);
}